// Round 15
// baseline (342.493 us; speedup 1.0000x reference)
//
#include <hip/hip_runtime.h>

// MoE-INR fused megakernel, bf16 MFMA (gfx950).
// Round 19: rolling e2-weight register prefetch + pol_s1/rf3 fusion on the
// r18 base (246us best). r18's explicit e2||e1 interleave was null -> the
// compiler already overlapped r15's calls; MFMA dependency is not the stall.
// Remaining candidate: section-START load latency (each heavy section begins
// with all waves waiting on fresh W loads; 2 waves/SIMD can't hide ~200-900
// cy). Fix: bpf[2][8] (64 VGPR of ~120 spare) holds e2[ex]'s b-frags; inside
// the k-loop each frag is USED then REFILLED with e2[ex+1]'s frag -- next
// section's e2 MFMAs start from registers, refill latency hidden under the
// full section. e1's loads (r18 split) then fly under e2's register-fed
// MFMAs. Also: pol_s1 fused into rf3 section (disjoint LDS: pol writes
// P[0,128), rf3 reads P+128/writes Q; saves 1 barrier, adds independent VALU
// to a load-bound section); convert grid back to 256 (r13's 1024 raised the
// bench-dispatch gap 60->75us across 5 samples).
// Pre-registered: WRITE_SIZE >10MB = spill -> revert prefetch. Flat+clean =
// structure at practical plateau (latency-bound, no saturated pipe).
// Kept: fused dual-tile wgemm2 (r15), split e1 mfma/epi (r18), 1x8 wave grid
// (r12), sin_rev + KSIN pre-scale (r9/r11), manual-RNE pack (r8 lesson),
// register-light gate (r6), atomic-free expert partials, (512,2) bounds.

typedef short v8s __attribute__((ext_vector_type(8)));
typedef float v4f __attribute__((ext_vector_type(4)));

#define KSIN 4.774648293f   // 30/(2*pi): sine-layer scale, folded into weights
#define AST 264             // LDS row stride in bf16 elements (16B-aligned rows)
#define PST 9               // probs row stride (floats)
#define N_CVT 8

__device__ __forceinline__ float bf2f(unsigned short h) {
  union { unsigned u; float f; } v; v.u = ((unsigned)h) << 16; return v.f;
}
__device__ __forceinline__ unsigned short f2bf(float f) {
  union { float f; unsigned u; } v; v.f = f;
  unsigned r = v.u + 0x7fffu + ((v.u >> 16) & 1u);  // RNE
  return (unsigned short)(r >> 16);
}
__device__ __forceinline__ unsigned pack2(float a, float b) {
  return (unsigned)f2bf(a) | ((unsigned)f2bf(b) << 16);  // manual RNE (verified)
}
__device__ __forceinline__ float sin_rev(float x) {  // sin(2*pi*x)
  return __builtin_amdgcn_sinf(x);
}
__device__ __forceinline__ float cos_rev(float x) {  // cos(2*pi*x)
  return __builtin_amdgcn_cosf(x);
}

struct CvtArgs {
  const float* src[N_CVT];
  unsigned     off[N_CVT];
  unsigned     n[N_CVT];
  float        scl[N_CVT];   // KSIN for sine-layer weights, 1.0 otherwise
};

__global__ void convert_kernel(CvtArgs a, unsigned short* __restrict__ dst) {
  const int tid = blockIdx.x * blockDim.x + threadIdx.x;
  const int stride = gridDim.x * blockDim.x;
  for (int k = 0; k < N_CVT; k++) {
    const unsigned n4 = a.n[k] >> 2;
    const float4* s = (const float4*)a.src[k];
    const float sc = a.scl[k];
    uint2* d = (uint2*)(dst + a.off[k]);
    for (unsigned i = tid; i < n4; i += stride) {
      float4 v = s[i];
      uint2 o; o.x = pack2(v.x * sc, v.y * sc); o.y = pack2(v.z * sc, v.w * sc);
      d[i] = o;
    }
    for (unsigned i = (n4 << 2) + tid; i < a.n[k]; i += stride)
      dst[a.off[k] + i] = f2bf(a.src[k][i] * sc);
  }
}

// ------------- fused dual-tile wave GEMM, 1x8 wave grid, RT=4 -------------
// Wave w computes O{0,1}[0:64, oc + w*NPW*16 : +NPW*16] for both tiles.
// b[ct] loaded ONCE per k0, feeds both tiles' MFMAs.
// Swapped operands: lane holds D[wcol=q*4+r][act_row=m15]; packed 8B stores.
// ACT: 0 = sin(2pi*(z + KSIN*b)) [W pre-scaled], 1 = relu, 2 = relu(z+skip)
template<int K, int NPW, int ACT>
__device__ __forceinline__ void wgemm2(const unsigned short* A0,
                                       const unsigned short* A1,
                                       unsigned short* O0, unsigned short* O1,
                                       int oc,
                                       const unsigned short* __restrict__ W,
                                       const float* __restrict__ bias,
                                       const unsigned short* skip0,
                                       const unsigned short* skip1) {
  const int lane = threadIdx.x & 63;
  const int wave = threadIdx.x >> 6;
  const int m15  = lane & 15;
  const int q    = lane >> 4;
  const int n0   = wave * (NPW * 16);
  v4f acc[2][NPW][4];
#pragma unroll
  for (int tl = 0; tl < 2; tl++)
#pragma unroll
    for (int i = 0; i < NPW; i++)
#pragma unroll
      for (int j = 0; j < 4; j++) acc[tl][i][j] = (v4f){0.f, 0.f, 0.f, 0.f};

#pragma unroll
  for (int k0 = 0; k0 < K / 32; ++k0) {
    v8s b[NPW], a0[4], a1[4];
#pragma unroll
    for (int ct = 0; ct < NPW; ct++)
      b[ct] = *(const v8s*)(W + (size_t)(n0 + ct * 16 + m15) * K + k0 * 32 + q * 8);
#pragma unroll
    for (int rt = 0; rt < 4; rt++) {
      a0[rt] = *(const v8s*)(A0 + (rt * 16 + m15) * AST + k0 * 32 + q * 8);
      a1[rt] = *(const v8s*)(A1 + (rt * 16 + m15) * AST + k0 * 32 + q * 8);
    }
#pragma unroll
    for (int ct = 0; ct < NPW; ct++)
#pragma unroll
      for (int rt = 0; rt < 4; rt++) {
        acc[0][ct][rt] = __builtin_amdgcn_mfma_f32_16x16x32_bf16(b[ct], a0[rt], acc[0][ct][rt], 0, 0, 0);
        acc[1][ct][rt] = __builtin_amdgcn_mfma_f32_16x16x32_bf16(b[ct], a1[rt], acc[1][ct][rt], 0, 0, 0);
      }
  }

#pragma unroll
  for (int ct = 0; ct < NPW; ct++) {
    const int c0 = n0 + ct * 16 + q * 4;
    v4f bv = *(const v4f*)(bias + c0);
    if (ACT == 0) bv *= KSIN;
#pragma unroll
    for (int rt = 0; rt < 4; rt++) {
      const int row = rt * 16 + m15;
#pragma unroll
      for (int tl = 0; tl < 2; tl++) {
        const v4f av = acc[tl][ct][rt];
        unsigned short* OUT = tl ? O1 : O0;
        const unsigned short* skip = tl ? skip1 : skip0;
        float o0, o1, o2, o3;
        if (ACT == 2) {
          const uint2 sk = *(const uint2*)(skip + row * AST + c0);
          o0 = fmaxf(av[0] + bv[0] + bf2f((unsigned short)(sk.x & 0xffffu)), 0.f);
          o1 = fmaxf(av[1] + bv[1] + bf2f((unsigned short)(sk.x >> 16)), 0.f);
          o2 = fmaxf(av[2] + bv[2] + bf2f((unsigned short)(sk.y & 0xffffu)), 0.f);
          o3 = fmaxf(av[3] + bv[3] + bf2f((unsigned short)(sk.y >> 16)), 0.f);
        } else if (ACT == 1) {
          o0 = fmaxf(av[0] + bv[0], 0.f);
          o1 = fmaxf(av[1] + bv[1], 0.f);
          o2 = fmaxf(av[2] + bv[2], 0.f);
          o3 = fmaxf(av[3] + bv[3], 0.f);
        } else {
          o0 = sin_rev(av[0] + bv[0]);
          o1 = sin_rev(av[1] + bv[1]);
          o2 = sin_rev(av[2] + bv[2]);
          o3 = sin_rev(av[3] + bv[3]);
        }
        uint2 w2; w2.x = pack2(o0, o1); w2.y = pack2(o2, o3);
        *(uint2*)(OUT + row * AST + oc + c0) = w2;
      }
    }
  }
}

// Prefetch all 16 b-frags of an expert-e2 weight matrix into registers.
__device__ __forceinline__ void e2_prefetch(const unsigned short* __restrict__ W,
                                            v8s (&bpf)[2][8]) {
  const int lane = threadIdx.x & 63;
  const int wave = threadIdx.x >> 6;
  const int m15  = lane & 15;
  const int q    = lane >> 4;
  const int n0   = wave * 32;
#pragma unroll
  for (int k0 = 0; k0 < 8; k0++)
#pragma unroll
    for (int ct = 0; ct < 2; ct++)
      bpf[ct][k0] = *(const v8s*)(W + (size_t)(n0 + ct * 16 + m15) * 256 + k0 * 32 + q * 8);
}

// Expert e1 MFMA only (K=256, NPW=2): acc stays in registers. Reads Q + W.
__device__ __forceinline__ void e1_mfma(const unsigned short* A0,
                                        const unsigned short* A1,
                                        const unsigned short* __restrict__ W,
                                        v4f (&acc)[2][2][4]) {
  const int lane = threadIdx.x & 63;
  const int wave = threadIdx.x >> 6;
  const int m15  = lane & 15;
  const int q    = lane >> 4;
  const int n0   = wave * 32;
#pragma unroll
  for (int tl = 0; tl < 2; tl++)
#pragma unroll
    for (int i = 0; i < 2; i++)
#pragma unroll
      for (int j = 0; j < 4; j++) acc[tl][i][j] = (v4f){0.f, 0.f, 0.f, 0.f};

#pragma unroll
  for (int k0 = 0; k0 < 8; ++k0) {
    v8s b[2], a0[4], a1[4];
#pragma unroll
    for (int ct = 0; ct < 2; ct++)
      b[ct] = *(const v8s*)(W + (size_t)(n0 + ct * 16 + m15) * 256 + k0 * 32 + q * 8);
#pragma unroll
    for (int rt = 0; rt < 4; rt++) {
      a0[rt] = *(const v8s*)(A0 + (rt * 16 + m15) * AST + k0 * 32 + q * 8);
      a1[rt] = *(const v8s*)(A1 + (rt * 16 + m15) * AST + k0 * 32 + q * 8);
    }
#pragma unroll
    for (int ct = 0; ct < 2; ct++)
#pragma unroll
      for (int rt = 0; rt < 4; rt++) {
        acc[0][ct][rt] = __builtin_amdgcn_mfma_f32_16x16x32_bf16(b[ct], a0[rt], acc[0][ct][rt], 0, 0, 0);
        acc[1][ct][rt] = __builtin_amdgcn_mfma_f32_16x16x32_bf16(b[ct], a1[rt], acc[1][ct][rt], 0, 0, 0);
      }
  }
}

// Expert e1 epilogue: sin + pack + P-write from registers.
__device__ __forceinline__ void e1_epi(const v4f (&acc)[2][2][4],
                                       const float* __restrict__ bias,
                                       unsigned short* O0, unsigned short* O1) {
  const int lane = threadIdx.x & 63;
  const int wave = threadIdx.x >> 6;
  const int m15  = lane & 15;
  const int q    = lane >> 4;
  const int n0   = wave * 32;
#pragma unroll
  for (int ct = 0; ct < 2; ct++) {
    const int c0 = n0 + ct * 16 + q * 4;
    v4f bv = *(const v4f*)(bias + c0);
    bv *= KSIN;
#pragma unroll
    for (int rt = 0; rt < 4; rt++) {
      const int row = rt * 16 + m15;
#pragma unroll
      for (int tl = 0; tl < 2; tl++) {
        const v4f av = acc[tl][ct][rt];
        unsigned short* OUT = tl ? O1 : O0;
        float o0 = sin_rev(av[0] + bv[0]);
        float o1 = sin_rev(av[1] + bv[1]);
        float o2 = sin_rev(av[2] + bv[2]);
        float o3 = sin_rev(av[3] + bv[3]);
        uint2 w2; w2.x = pack2(o0, o1); w2.y = pack2(o2, o3);
        *(uint2*)(OUT + row * AST + c0) = w2;
      }
    }
  }
}

// Expert e2 (sine, W pre-scaled) + final 256->1 dot, b-frags from REGISTERS.
// Each bpf[ct][k0] is used then REFILLED with the next expert's frag (rolling
// single-buffer prefetch: refill latency hides under the whole section).
__device__ __forceinline__ void wexpert2p(const unsigned short* A0,
                                          const unsigned short* A1,
                                          v8s (&bpf)[2][8],
                                          const unsigned short* __restrict__ Wnext,
                                          const float* __restrict__ bias,
                                          const float* __restrict__ wfin,
                                          float* __restrict__ pp0,
                                          float* __restrict__ pp1) {
  const int lane = threadIdx.x & 63;
  const int wave = threadIdx.x >> 6;
  const int m15  = lane & 15;
  const int q    = lane >> 4;
  const int n0   = wave * 32;
  v4f acc[2][2][4];
#pragma unroll
  for (int tl = 0; tl < 2; tl++)
#pragma unroll
    for (int i = 0; i < 2; i++)
#pragma unroll
      for (int j = 0; j < 4; j++) acc[tl][i][j] = (v4f){0.f, 0.f, 0.f, 0.f};

#pragma unroll
  for (int k0 = 0; k0 < 8; ++k0) {
    v8s a0[4], a1[4];
#pragma unroll
    for (int rt = 0; rt < 4; rt++) {
      a0[rt] = *(const v8s*)(A0 + (rt * 16 + m15) * AST + k0 * 32 + q * 8);
      a1[rt] = *(const v8s*)(A1 + (rt * 16 + m15) * AST + k0 * 32 + q * 8);
    }
    const v8s b0 = bpf[0][k0];
    const v8s b1 = bpf[1][k0];
    // rolling refill for the NEXT expert (consumed next section)
    bpf[0][k0] = *(const v8s*)(Wnext + (size_t)(n0 + m15) * 256 + k0 * 32 + q * 8);
    bpf[1][k0] = *(const v8s*)(Wnext + (size_t)(n0 + 16 + m15) * 256 + k0 * 32 + q * 8);
#pragma unroll
    for (int rt = 0; rt < 4; rt++) {
      acc[0][0][rt] = __builtin_amdgcn_mfma_f32_16x16x32_bf16(b0, a0[rt], acc[0][0][rt], 0, 0, 0);
      acc[1][0][rt] = __builtin_amdgcn_mfma_f32_16x16x32_bf16(b0, a1[rt], acc[1][0][rt], 0, 0, 0);
      acc[0][1][rt] = __builtin_amdgcn_mfma_f32_16x16x32_bf16(b1, a0[rt], acc[0][1][rt], 0, 0, 0);
      acc[1][1][rt] = __builtin_amdgcn_mfma_f32_16x16x32_bf16(b1, a1[rt], acc[1][1][rt], 0, 0, 0);
    }
  }

  float p0[4] = {0.f, 0.f, 0.f, 0.f};
  float p1[4] = {0.f, 0.f, 0.f, 0.f};
#pragma unroll
  for (int ct = 0; ct < 2; ct++) {
    const int c0 = n0 + ct * 16 + q * 4;
    v4f bv = *(const v4f*)(bias + c0);
    bv *= KSIN;
    const v4f wf = *(const v4f*)(wfin + c0);
#pragma unroll
    for (int rt = 0; rt < 4; rt++)
#pragma unroll
      for (int r = 0; r < 4; r++) {
        p0[rt] += sin_rev(acc[0][ct][rt][r] + bv[r]) * wf[r];
        p1[rt] += sin_rev(acc[1][ct][rt][r] + bv[r]) * wf[r];
      }
  }
  // reduce over q (lanes 16 apart hold same act_row, different cols)
#pragma unroll
  for (int rt = 0; rt < 4; rt++) {
    float v0 = p0[rt], v1 = p1[rt];
    v0 += __shfl_xor(v0, 16);
    v0 += __shfl_xor(v0, 32);
    v1 += __shfl_xor(v1, 16);
    v1 += __shfl_xor(v1, 32);
    if (q == 0) {
      pp0[wave * 64 + rt * 16 + m15] = v0;
      pp1[wave * 64 + rt * 16 + m15] = v1;
    }
  }
}

__global__ __launch_bounds__(512, 2) void moe_inr_kernel(
    const float* __restrict__ x,
    const unsigned short* __restrict__ es1w, const float* __restrict__ es1b,
    const unsigned short* __restrict__ es2w, const float* __restrict__ es2b,
    const unsigned short* __restrict__ rf1w, const float* __restrict__ rf1b,
    const unsigned short* __restrict__ rf2w, const float* __restrict__ rf2b,
    const unsigned short* __restrict__ rf3w, const float* __restrict__ rf3b,
    const float* __restrict__ ps1w,          const float* __restrict__ ps1b,
    const unsigned short* __restrict__ ps2w, const float* __restrict__ ps2b,
    const float* __restrict__ gw,            const float* __restrict__ gb,
    const unsigned short* __restrict__ xs1w, const float* __restrict__ xs1b,
    const unsigned short* __restrict__ xs2w, const float* __restrict__ xs2b,
    const float* __restrict__ xfw,           const float* __restrict__ xfb,
    float* __restrict__ out) {
  __shared__ __align__(16) unsigned short P[2][64 * AST];
  __shared__ __align__(16) unsigned short Q[2][64 * AST];
  __shared__ float probs[2][64 * PST];
  __shared__ float pred_part[2][8 * 64];

  const int t   = threadIdx.x;
  const int r0g = blockIdx.x * 128;   // two 64-row tiles

  // Stage 0: positional encoding -> P[tl] cols [0,64), both tiles.
#pragma unroll
  for (int tl = 0; tl < 2; ++tl) {
    const int row = t & 63, g = t >> 6, c = g & 3, jh = g >> 2;
    const float xv = x[(r0g + tl * 64 + row) * 4 + c];
    float sn[4], cs[4];
#pragma unroll
    for (int jj = 0; jj < 4; jj++) {
      const int j = jh * 4 + jj;
      const float rev = xv * (0.5f * (float)(1 << j));
      sn[jj] = sin_rev(rev);
      cs[jj] = cos_rev(rev);
    }
    uint2 ws; ws.x = pack2(sn[0], sn[1]); ws.y = pack2(sn[2], sn[3]);
    uint2 wc2; wc2.x = pack2(cs[0], cs[1]); wc2.y = pack2(cs[2], cs[3]);
    *(uint2*)(P[tl] + row * AST + c * 16 + jh * 4) = ws;
    *(uint2*)(P[tl] + row * AST + c * 16 + 8 + jh * 4) = wc2;
  }
  __syncthreads();
  wgemm2<64, 1, 0>(P[0], P[1], P[0], P[1], 64, es1w, es1b, nullptr, nullptr);
  __syncthreads();
  wgemm2<128, 2, 0>(P[0] + 64, P[1] + 64, Q[0], Q[1], 0, es2w, es2b, nullptr, nullptr);
  __syncthreads();
  wgemm2<256, 1, 1>(Q[0], Q[1], P[0], P[1], 0, rf1w, rf1b, nullptr, nullptr);
  __syncthreads();
  wgemm2<128, 1, 1>(P[0], P[1], P[0], P[1], 128, rf2w, rf2b, nullptr, nullptr);
  __syncthreads();
  // rf3 section + fused pol_s1: rf3 reads P[tl]+128 / writes Q[tl]; pol_s1
  // writes P[tl][0,128) (r1 dead after rf2) -- disjoint, no barrier needed.
  wgemm2<128, 2, 2>(P[0] + 128, P[1] + 128, Q[0], Q[1], 0, rf3w, rf3b, Q[0], Q[1]);
#pragma unroll
  for (int tl = 0; tl < 2; ++tl) {
    const int row = t & 63, g = t >> 6;
    const v4f xv = *(const v4f*)(x + (r0g + tl * 64 + row) * 4);
#pragma unroll
    for (int ii = 0; ii < 4; ii++) {
      float oo[4];
#pragma unroll
      for (int i2 = 0; i2 < 4; i2++) {
        const int o = g * 16 + ii * 4 + i2;
        const v4f w4 = *(const v4f*)(ps1w + o * 4);
        const float z = xv[0] * w4[0] + xv[1] * w4[1] + xv[2] * w4[2] +
                        xv[3] * w4[3] + ps1b[o];
        oo[i2] = sin_rev(KSIN * z);
      }
      uint2 w2; w2.x = pack2(oo[0], oo[1]); w2.y = pack2(oo[2], oo[3]);
      *(uint2*)(P[tl] + row * AST + g * 16 + ii * 4) = w2;
    }
  }
  __syncthreads();
  wgemm2<128, 1, 0>(P[0], P[1], P[0], P[1], 128, ps2w, ps2b, nullptr, nullptr);
  __syncthreads();
  // gate (f32 weights): per tile, 8 partial-threads per row, 48 k each.
#pragma unroll
  for (int tl = 0; tl < 2; ++tl) {
    const int row = t >> 3, pp = t & 7;
    float lg[7] = {0.f, 0.f, 0.f, 0.f, 0.f, 0.f, 0.f};
#pragma unroll
    for (int u = 0; u < 6; u++) {
      const int kk = pp * 48 + u * 8;
      const v8s av = (kk < 256) ? *(const v8s*)(Q[tl] + row * AST + kk)
                                : *(const v8s*)(P[tl] + row * AST + 128 + (kk - 256));
      float af[8];
#pragma unroll
      for (int e2 = 0; e2 < 8; e2++) af[e2] = bf2f((unsigned short)av[e2]);
#pragma unroll
      for (int j = 0; j < 7; j++) {
        const v4f g0 = *(const v4f*)(gw + j * 384 + kk);
        const v4f g1 = *(const v4f*)(gw + j * 384 + kk + 4);
        lg[j] += af[0] * g0[0] + af[1] * g0[1] + af[2] * g0[2] + af[3] * g0[3] +
                 af[4] * g1[0] + af[5] * g1[1] + af[6] * g1[2] + af[7] * g1[3];
      }
    }
#pragma unroll
    for (int j = 0; j < 7; j++) {
      float s = lg[j];
      s += __shfl_xor(s, 1);
      s += __shfl_xor(s, 2);
      s += __shfl_xor(s, 4);
      lg[j] = s;
    }
    if (pp == 0) {
#pragma unroll
      for (int j = 0; j < 7; j++) probs[tl][row * PST + j] = lg[j] + gb[j];
    }
  }
  __syncthreads();
  // Section S0: e1[0] MFMA (reads Q) + e2[0] b-prefetch + softmax (regs/probs)
  // + e1[0] epilogue -> P. Gate finished reading P at the barrier above.
  float yr = 0.f;
  v4f acc1[2][2][4];
  v8s bpf[2][8];
  e1_mfma(Q[0], Q[1], xs1w, acc1);
  e2_prefetch(xs2w, bpf);
  if (t < 128) {  // softmax over 7, tile = t>>6, row = t&63
    const int tl = t >> 6, row = t & 63;
    float m = probs[tl][row * PST];
#pragma unroll
    for (int j = 1; j < 7; j++) m = fmaxf(m, probs[tl][row * PST + j]);
    float s = 0.f, e[7];
#pragma unroll
    for (int j = 0; j < 7; j++) { e[j] = __expf(probs[tl][row * PST + j] - m); s += e[j]; }
    const float inv = 1.f / s;
#pragma unroll
    for (int j = 0; j < 7; j++) probs[tl][row * PST + j] = e[j] * inv;
  }
  e1_epi(acc1, xs1b, P[0], P[1]);
  __syncthreads();
  // Pipelined expert loop: {e2[ex] (b from regs, rolling refill of e2[ex+1])
  // || e1_mfma[ex+1]} -> bar -> {e1_epi[ex+1] -> P ; yr += pred} -> bar.
  for (int ex = 0; ex < 7; ++ex) {
    const int nxt = (ex < 6) ? ex + 1 : 6;
    wexpert2p(P[0], P[1], bpf, xs2w + nxt * 65536,
              xs2b + ex * 256, xfw + ex * 256, pred_part[0], pred_part[1]);
    if (ex < 6) e1_mfma(Q[0], Q[1], xs1w + (ex + 1) * 65536, acc1);
    __syncthreads();
    if (ex < 6) e1_epi(acc1, xs1b + (ex + 1) * 256, P[0], P[1]);
    if (t < 128) {
      const int tl = t >> 6, row = t & 63;
      float pr = 0.f;
#pragma unroll
      for (int w = 0; w < 8; w++) pr += pred_part[tl][w * 64 + row];
      yr += (pr + xfb[ex]) * probs[tl][row * PST + ex];
    }
    if (ex < 6) __syncthreads();
  }
  if (t < 128) out[r0g + t] = yr;
}

extern "C" void kernel_launch(void* const* d_in, const int* in_sizes, int n_in,
                              void* d_out, int out_size, void* d_ws, size_t ws_size,
                              hipStream_t stream) {
  (void)out_size; (void)n_in; (void)ws_size;
  const int   idx[N_CVT] = {1, 3, 5, 7, 9, 13, 17, 19};
  // KSIN folded into sine-layer weights (enc_s1, enc_s2, pol_s2, exp_s1, exp_s2)
  const float scl[N_CVT] = {KSIN, KSIN, 1.f, 1.f, 1.f, KSIN, KSIN, KSIN};
  unsigned off[N_CVT], cur = 0;
  CvtArgs a;
  for (int i = 0; i < N_CVT; i++) {
    off[i] = cur;
    a.src[i] = (const float*)d_in[idx[i]];
    a.off[i] = cur;
    a.n[i]   = (unsigned)in_sizes[idx[i]];
    a.scl[i] = scl[i];
    cur += ((unsigned)in_sizes[idx[i]] + 7u) & ~7u;  // 16B-align each array
  }
  unsigned short* dst = (unsigned short*)d_ws;
  hipLaunchKernelGGL(convert_kernel, dim3(256), dim3(256), 0, stream, a, dst);
  hipLaunchKernelGGL(moe_inr_kernel, dim3(65536 / 128), dim3(512), 0, stream,
      (const float*)d_in[0],
      dst + off[0], (const float*)d_in[2],
      dst + off[1], (const float*)d_in[4],
      dst + off[2], (const float*)d_in[6],
      dst + off[3], (const float*)d_in[8],
      dst + off[4], (const float*)d_in[10],
      (const float*)d_in[11], (const float*)d_in[12],
      dst + off[5], (const float*)d_in[14],
      (const float*)d_in[15], (const float*)d_in[16],
      dst + off[6], (const float*)d_in[18],
      dst + off[7], (const float*)d_in[20],
      (const float*)d_in[21], (const float*)d_in[22],
      (float*)d_out);
}

// Round 16
// 322.538 us; speedup vs baseline: 1.0619x; 1.0619x over previous
//
#include <hip/hip_runtime.h>

// MoE-INR fused megakernel, bf16 MFMA (gfx950).
// Round 20: consolidation. r19's rolling e2-b-prefetch SPILLED (WRITE 256KB
// ->23.7MB, +37us) exactly per the pre-registered signature -> reverted to
// r18's wexpert2d (246us best). Kept from r19 (register-neutral, low-risk):
//  (a) pol_s1 fused into rf3 section (disjoint LDS: pol writes P[0,128)
//      where r1 is dead post-rf2; rf3 reads P+128/writes Q; saves 1 barrier);
//  (b) convert grid 256 (bench-dispatch gap 60-68us at 256 vs 75-80 at 1024
//      across r6/r11 vs r13/r15/r18).
// Register-budget lesson (r19 + r9/r10): at ~200 live VGPRs every deeper
// prefetch/double-buffer idea spills; that door is closed by the budget.
// Structure summary (verified levers): dual 64-row tiles 1 blk/CU (r13,
// +27%), k0-level b-share across tiles (r15, +9%), e1 mfma/epi split with
// e2||e1 interleave (r18, +1%), sin_rev+KSIN fold (r9), manual-RNE pack
// (r8), register-light gate (r6). Dead ends (measured): col-split grids
// (r12/r16: global b-load count dominates), occupancy raising (r7), A-read
// reduction (r16/r17: LDS port not critical), reg prefetch (r19: spills).

typedef short v8s __attribute__((ext_vector_type(8)));
typedef float v4f __attribute__((ext_vector_type(4)));

#define KSIN 4.774648293f   // 30/(2*pi): sine-layer scale, folded into weights
#define AST 264             // LDS row stride in bf16 elements (16B-aligned rows)
#define PST 9               // probs row stride (floats)
#define N_CVT 8

__device__ __forceinline__ float bf2f(unsigned short h) {
  union { unsigned u; float f; } v; v.u = ((unsigned)h) << 16; return v.f;
}
__device__ __forceinline__ unsigned short f2bf(float f) {
  union { float f; unsigned u; } v; v.f = f;
  unsigned r = v.u + 0x7fffu + ((v.u >> 16) & 1u);  // RNE
  return (unsigned short)(r >> 16);
}
__device__ __forceinline__ unsigned pack2(float a, float b) {
  return (unsigned)f2bf(a) | ((unsigned)f2bf(b) << 16);  // manual RNE (verified)
}
__device__ __forceinline__ float sin_rev(float x) {  // sin(2*pi*x)
  return __builtin_amdgcn_sinf(x);
}
__device__ __forceinline__ float cos_rev(float x) {  // cos(2*pi*x)
  return __builtin_amdgcn_cosf(x);
}

struct CvtArgs {
  const float* src[N_CVT];
  unsigned     off[N_CVT];
  unsigned     n[N_CVT];
  float        scl[N_CVT];   // KSIN for sine-layer weights, 1.0 otherwise
};

__global__ void convert_kernel(CvtArgs a, unsigned short* __restrict__ dst) {
  const int tid = blockIdx.x * blockDim.x + threadIdx.x;
  const int stride = gridDim.x * blockDim.x;
  for (int k = 0; k < N_CVT; k++) {
    const unsigned n4 = a.n[k] >> 2;
    const float4* s = (const float4*)a.src[k];
    const float sc = a.scl[k];
    uint2* d = (uint2*)(dst + a.off[k]);
    for (unsigned i = tid; i < n4; i += stride) {
      float4 v = s[i];
      uint2 o; o.x = pack2(v.x * sc, v.y * sc); o.y = pack2(v.z * sc, v.w * sc);
      d[i] = o;
    }
    for (unsigned i = (n4 << 2) + tid; i < a.n[k]; i += stride)
      dst[a.off[k] + i] = f2bf(a.src[k][i] * sc);
  }
}

// ------------- fused dual-tile wave GEMM, 1x8 wave grid, RT=4 -------------
// Wave w computes O{0,1}[0:64, oc + w*NPW*16 : +NPW*16] for both tiles.
// b[ct] loaded ONCE per k0, feeds both tiles' MFMAs.
// Swapped operands: lane holds D[wcol=q*4+r][act_row=m15]; packed 8B stores.
// ACT: 0 = sin(2pi*(z + KSIN*b)) [W pre-scaled], 1 = relu, 2 = relu(z+skip)
template<int K, int NPW, int ACT>
__device__ __forceinline__ void wgemm2(const unsigned short* A0,
                                       const unsigned short* A1,
                                       unsigned short* O0, unsigned short* O1,
                                       int oc,
                                       const unsigned short* __restrict__ W,
                                       const float* __restrict__ bias,
                                       const unsigned short* skip0,
                                       const unsigned short* skip1) {
  const int lane = threadIdx.x & 63;
  const int wave = threadIdx.x >> 6;
  const int m15  = lane & 15;
  const int q    = lane >> 4;
  const int n0   = wave * (NPW * 16);
  v4f acc[2][NPW][4];
#pragma unroll
  for (int tl = 0; tl < 2; tl++)
#pragma unroll
    for (int i = 0; i < NPW; i++)
#pragma unroll
      for (int j = 0; j < 4; j++) acc[tl][i][j] = (v4f){0.f, 0.f, 0.f, 0.f};

#pragma unroll
  for (int k0 = 0; k0 < K / 32; ++k0) {
    v8s b[NPW], a0[4], a1[4];
#pragma unroll
    for (int ct = 0; ct < NPW; ct++)
      b[ct] = *(const v8s*)(W + (size_t)(n0 + ct * 16 + m15) * K + k0 * 32 + q * 8);
#pragma unroll
    for (int rt = 0; rt < 4; rt++) {
      a0[rt] = *(const v8s*)(A0 + (rt * 16 + m15) * AST + k0 * 32 + q * 8);
      a1[rt] = *(const v8s*)(A1 + (rt * 16 + m15) * AST + k0 * 32 + q * 8);
    }
#pragma unroll
    for (int ct = 0; ct < NPW; ct++)
#pragma unroll
      for (int rt = 0; rt < 4; rt++) {
        acc[0][ct][rt] = __builtin_amdgcn_mfma_f32_16x16x32_bf16(b[ct], a0[rt], acc[0][ct][rt], 0, 0, 0);
        acc[1][ct][rt] = __builtin_amdgcn_mfma_f32_16x16x32_bf16(b[ct], a1[rt], acc[1][ct][rt], 0, 0, 0);
      }
  }

#pragma unroll
  for (int ct = 0; ct < NPW; ct++) {
    const int c0 = n0 + ct * 16 + q * 4;
    v4f bv = *(const v4f*)(bias + c0);
    if (ACT == 0) bv *= KSIN;
#pragma unroll
    for (int rt = 0; rt < 4; rt++) {
      const int row = rt * 16 + m15;
#pragma unroll
      for (int tl = 0; tl < 2; tl++) {
        const v4f av = acc[tl][ct][rt];
        unsigned short* OUT = tl ? O1 : O0;
        const unsigned short* skip = tl ? skip1 : skip0;
        float o0, o1, o2, o3;
        if (ACT == 2) {
          const uint2 sk = *(const uint2*)(skip + row * AST + c0);
          o0 = fmaxf(av[0] + bv[0] + bf2f((unsigned short)(sk.x & 0xffffu)), 0.f);
          o1 = fmaxf(av[1] + bv[1] + bf2f((unsigned short)(sk.x >> 16)), 0.f);
          o2 = fmaxf(av[2] + bv[2] + bf2f((unsigned short)(sk.y & 0xffffu)), 0.f);
          o3 = fmaxf(av[3] + bv[3] + bf2f((unsigned short)(sk.y >> 16)), 0.f);
        } else if (ACT == 1) {
          o0 = fmaxf(av[0] + bv[0], 0.f);
          o1 = fmaxf(av[1] + bv[1], 0.f);
          o2 = fmaxf(av[2] + bv[2], 0.f);
          o3 = fmaxf(av[3] + bv[3], 0.f);
        } else {
          o0 = sin_rev(av[0] + bv[0]);
          o1 = sin_rev(av[1] + bv[1]);
          o2 = sin_rev(av[2] + bv[2]);
          o3 = sin_rev(av[3] + bv[3]);
        }
        uint2 w2; w2.x = pack2(o0, o1); w2.y = pack2(o2, o3);
        *(uint2*)(OUT + row * AST + oc + c0) = w2;
      }
    }
  }
}

// Expert e1 MFMA only (K=256, NPW=2): acc stays in registers. Reads Q + W.
__device__ __forceinline__ void e1_mfma(const unsigned short* A0,
                                        const unsigned short* A1,
                                        const unsigned short* __restrict__ W,
                                        v4f (&acc)[2][2][4]) {
  const int lane = threadIdx.x & 63;
  const int wave = threadIdx.x >> 6;
  const int m15  = lane & 15;
  const int q    = lane >> 4;
  const int n0   = wave * 32;
#pragma unroll
  for (int tl = 0; tl < 2; tl++)
#pragma unroll
    for (int i = 0; i < 2; i++)
#pragma unroll
      for (int j = 0; j < 4; j++) acc[tl][i][j] = (v4f){0.f, 0.f, 0.f, 0.f};

#pragma unroll
  for (int k0 = 0; k0 < 8; ++k0) {
    v8s b[2], a0[4], a1[4];
#pragma unroll
    for (int ct = 0; ct < 2; ct++)
      b[ct] = *(const v8s*)(W + (size_t)(n0 + ct * 16 + m15) * 256 + k0 * 32 + q * 8);
#pragma unroll
    for (int rt = 0; rt < 4; rt++) {
      a0[rt] = *(const v8s*)(A0 + (rt * 16 + m15) * AST + k0 * 32 + q * 8);
      a1[rt] = *(const v8s*)(A1 + (rt * 16 + m15) * AST + k0 * 32 + q * 8);
    }
#pragma unroll
    for (int ct = 0; ct < 2; ct++)
#pragma unroll
      for (int rt = 0; rt < 4; rt++) {
        acc[0][ct][rt] = __builtin_amdgcn_mfma_f32_16x16x32_bf16(b[ct], a0[rt], acc[0][ct][rt], 0, 0, 0);
        acc[1][ct][rt] = __builtin_amdgcn_mfma_f32_16x16x32_bf16(b[ct], a1[rt], acc[1][ct][rt], 0, 0, 0);
      }
  }
}

// Expert e1 epilogue: sin + pack + P-write from registers.
__device__ __forceinline__ void e1_epi(const v4f (&acc)[2][2][4],
                                       const float* __restrict__ bias,
                                       unsigned short* O0, unsigned short* O1) {
  const int lane = threadIdx.x & 63;
  const int wave = threadIdx.x >> 6;
  const int m15  = lane & 15;
  const int q    = lane >> 4;
  const int n0   = wave * 32;
#pragma unroll
  for (int ct = 0; ct < 2; ct++) {
    const int c0 = n0 + ct * 16 + q * 4;
    v4f bv = *(const v4f*)(bias + c0);
    bv *= KSIN;
#pragma unroll
    for (int rt = 0; rt < 4; rt++) {
      const int row = rt * 16 + m15;
#pragma unroll
      for (int tl = 0; tl < 2; tl++) {
        const v4f av = acc[tl][ct][rt];
        unsigned short* OUT = tl ? O1 : O0;
        float o0 = sin_rev(av[0] + bv[0]);
        float o1 = sin_rev(av[1] + bv[1]);
        float o2 = sin_rev(av[2] + bv[2]);
        float o3 = sin_rev(av[3] + bv[3]);
        uint2 w2; w2.x = pack2(o0, o1); w2.y = pack2(o2, o3);
        *(uint2*)(OUT + row * AST + c0) = w2;
      }
    }
  }
}

// Fused dual-tile expert layer 2 (sine, W pre-scaled) + final 256->1 dot.
// Wave owns 32 unique cols; b loaded once per k0 for both tiles.
// Per-row partial sums -> pp{0,1}[wave][row] (no atomics).
__device__ __forceinline__ void wexpert2d(const unsigned short* A0,
                                          const unsigned short* A1,
                                          const unsigned short* __restrict__ W,
                                          const float* __restrict__ bias,
                                          const float* __restrict__ wfin,
                                          float* __restrict__ pp0,
                                          float* __restrict__ pp1) {
  const int lane = threadIdx.x & 63;
  const int wave = threadIdx.x >> 6;
  const int m15  = lane & 15;
  const int q    = lane >> 4;
  const int n0   = wave * 32;
  v4f acc[2][2][4];
#pragma unroll
  for (int tl = 0; tl < 2; tl++)
#pragma unroll
    for (int i = 0; i < 2; i++)
#pragma unroll
      for (int j = 0; j < 4; j++) acc[tl][i][j] = (v4f){0.f, 0.f, 0.f, 0.f};

#pragma unroll
  for (int k0 = 0; k0 < 8; ++k0) {
    v8s b[2], a0[4], a1[4];
#pragma unroll
    for (int ct = 0; ct < 2; ct++)
      b[ct] = *(const v8s*)(W + (size_t)(n0 + ct * 16 + m15) * 256 + k0 * 32 + q * 8);
#pragma unroll
    for (int rt = 0; rt < 4; rt++) {
      a0[rt] = *(const v8s*)(A0 + (rt * 16 + m15) * AST + k0 * 32 + q * 8);
      a1[rt] = *(const v8s*)(A1 + (rt * 16 + m15) * AST + k0 * 32 + q * 8);
    }
#pragma unroll
    for (int ct = 0; ct < 2; ct++)
#pragma unroll
      for (int rt = 0; rt < 4; rt++) {
        acc[0][ct][rt] = __builtin_amdgcn_mfma_f32_16x16x32_bf16(b[ct], a0[rt], acc[0][ct][rt], 0, 0, 0);
        acc[1][ct][rt] = __builtin_amdgcn_mfma_f32_16x16x32_bf16(b[ct], a1[rt], acc[1][ct][rt], 0, 0, 0);
      }
  }

  float p0[4] = {0.f, 0.f, 0.f, 0.f};
  float p1[4] = {0.f, 0.f, 0.f, 0.f};
#pragma unroll
  for (int ct = 0; ct < 2; ct++) {
    const int c0 = n0 + ct * 16 + q * 4;
    v4f bv = *(const v4f*)(bias + c0);
    bv *= KSIN;
    const v4f wf = *(const v4f*)(wfin + c0);
#pragma unroll
    for (int rt = 0; rt < 4; rt++)
#pragma unroll
      for (int r = 0; r < 4; r++) {
        p0[rt] += sin_rev(acc[0][ct][rt][r] + bv[r]) * wf[r];
        p1[rt] += sin_rev(acc[1][ct][rt][r] + bv[r]) * wf[r];
      }
  }
  // reduce over q (lanes 16 apart hold same act_row, different cols)
#pragma unroll
  for (int rt = 0; rt < 4; rt++) {
    float v0 = p0[rt], v1 = p1[rt];
    v0 += __shfl_xor(v0, 16);
    v0 += __shfl_xor(v0, 32);
    v1 += __shfl_xor(v1, 16);
    v1 += __shfl_xor(v1, 32);
    if (q == 0) {
      pp0[wave * 64 + rt * 16 + m15] = v0;
      pp1[wave * 64 + rt * 16 + m15] = v1;
    }
  }
}

__global__ __launch_bounds__(512, 2) void moe_inr_kernel(
    const float* __restrict__ x,
    const unsigned short* __restrict__ es1w, const float* __restrict__ es1b,
    const unsigned short* __restrict__ es2w, const float* __restrict__ es2b,
    const unsigned short* __restrict__ rf1w, const float* __restrict__ rf1b,
    const unsigned short* __restrict__ rf2w, const float* __restrict__ rf2b,
    const unsigned short* __restrict__ rf3w, const float* __restrict__ rf3b,
    const float* __restrict__ ps1w,          const float* __restrict__ ps1b,
    const unsigned short* __restrict__ ps2w, const float* __restrict__ ps2b,
    const float* __restrict__ gw,            const float* __restrict__ gb,
    const unsigned short* __restrict__ xs1w, const float* __restrict__ xs1b,
    const unsigned short* __restrict__ xs2w, const float* __restrict__ xs2b,
    const float* __restrict__ xfw,           const float* __restrict__ xfb,
    float* __restrict__ out) {
  __shared__ __align__(16) unsigned short P[2][64 * AST];
  __shared__ __align__(16) unsigned short Q[2][64 * AST];
  __shared__ float probs[2][64 * PST];
  __shared__ float pred_part[2][8 * 64];

  const int t   = threadIdx.x;
  const int r0g = blockIdx.x * 128;   // two 64-row tiles

  // Stage 0: positional encoding -> P[tl] cols [0,64), both tiles.
#pragma unroll
  for (int tl = 0; tl < 2; ++tl) {
    const int row = t & 63, g = t >> 6, c = g & 3, jh = g >> 2;
    const float xv = x[(r0g + tl * 64 + row) * 4 + c];
    float sn[4], cs[4];
#pragma unroll
    for (int jj = 0; jj < 4; jj++) {
      const int j = jh * 4 + jj;
      const float rev = xv * (0.5f * (float)(1 << j));
      sn[jj] = sin_rev(rev);
      cs[jj] = cos_rev(rev);
    }
    uint2 ws; ws.x = pack2(sn[0], sn[1]); ws.y = pack2(sn[2], sn[3]);
    uint2 wc2; wc2.x = pack2(cs[0], cs[1]); wc2.y = pack2(cs[2], cs[3]);
    *(uint2*)(P[tl] + row * AST + c * 16 + jh * 4) = ws;
    *(uint2*)(P[tl] + row * AST + c * 16 + 8 + jh * 4) = wc2;
  }
  __syncthreads();
  wgemm2<64, 1, 0>(P[0], P[1], P[0], P[1], 64, es1w, es1b, nullptr, nullptr);
  __syncthreads();
  wgemm2<128, 2, 0>(P[0] + 64, P[1] + 64, Q[0], Q[1], 0, es2w, es2b, nullptr, nullptr);
  __syncthreads();
  wgemm2<256, 1, 1>(Q[0], Q[1], P[0], P[1], 0, rf1w, rf1b, nullptr, nullptr);
  __syncthreads();
  wgemm2<128, 1, 1>(P[0], P[1], P[0], P[1], 128, rf2w, rf2b, nullptr, nullptr);
  __syncthreads();
  // rf3 section + fused pol_s1: rf3 reads P[tl]+128 / writes Q[tl]; pol_s1
  // writes P[tl][0,128) (r1 dead after rf2) -- disjoint, no barrier needed.
  wgemm2<128, 2, 2>(P[0] + 128, P[1] + 128, Q[0], Q[1], 0, rf3w, rf3b, Q[0], Q[1]);
#pragma unroll
  for (int tl = 0; tl < 2; ++tl) {
    const int row = t & 63, g = t >> 6;
    const v4f xv = *(const v4f*)(x + (r0g + tl * 64 + row) * 4);
#pragma unroll
    for (int ii = 0; ii < 4; ii++) {
      float oo[4];
#pragma unroll
      for (int i2 = 0; i2 < 4; i2++) {
        const int o = g * 16 + ii * 4 + i2;
        const v4f w4 = *(const v4f*)(ps1w + o * 4);
        const float z = xv[0] * w4[0] + xv[1] * w4[1] + xv[2] * w4[2] +
                        xv[3] * w4[3] + ps1b[o];
        oo[i2] = sin_rev(KSIN * z);
      }
      uint2 w2; w2.x = pack2(oo[0], oo[1]); w2.y = pack2(oo[2], oo[3]);
      *(uint2*)(P[tl] + row * AST + g * 16 + ii * 4) = w2;
    }
  }
  __syncthreads();
  wgemm2<128, 1, 0>(P[0], P[1], P[0], P[1], 128, ps2w, ps2b, nullptr, nullptr);
  __syncthreads();
  // gate (f32 weights): per tile, 8 partial-threads per row, 48 k each.
#pragma unroll
  for (int tl = 0; tl < 2; ++tl) {
    const int row = t >> 3, pp = t & 7;
    float lg[7] = {0.f, 0.f, 0.f, 0.f, 0.f, 0.f, 0.f};
#pragma unroll
    for (int u = 0; u < 6; u++) {
      const int kk = pp * 48 + u * 8;
      const v8s av = (kk < 256) ? *(const v8s*)(Q[tl] + row * AST + kk)
                                : *(const v8s*)(P[tl] + row * AST + 128 + (kk - 256));
      float af[8];
#pragma unroll
      for (int e2 = 0; e2 < 8; e2++) af[e2] = bf2f((unsigned short)av[e2]);
#pragma unroll
      for (int j = 0; j < 7; j++) {
        const v4f g0 = *(const v4f*)(gw + j * 384 + kk);
        const v4f g1 = *(const v4f*)(gw + j * 384 + kk + 4);
        lg[j] += af[0] * g0[0] + af[1] * g0[1] + af[2] * g0[2] + af[3] * g0[3] +
                 af[4] * g1[0] + af[5] * g1[1] + af[6] * g1[2] + af[7] * g1[3];
      }
    }
#pragma unroll
    for (int j = 0; j < 7; j++) {
      float s = lg[j];
      s += __shfl_xor(s, 1);
      s += __shfl_xor(s, 2);
      s += __shfl_xor(s, 4);
      lg[j] = s;
    }
    if (pp == 0) {
#pragma unroll
      for (int j = 0; j < 7; j++) probs[tl][row * PST + j] = lg[j] + gb[j];
    }
  }
  __syncthreads();
  // Section S0: e1[0] MFMA (reads Q) + softmax (regs/probs) + e1[0] epi -> P.
  float yr = 0.f;
  v4f acc1[2][2][4];
  e1_mfma(Q[0], Q[1], xs1w, acc1);
  if (t < 128) {  // softmax over 7, tile = t>>6, row = t&63
    const int tl = t >> 6, row = t & 63;
    float m = probs[tl][row * PST];
#pragma unroll
    for (int j = 1; j < 7; j++) m = fmaxf(m, probs[tl][row * PST + j]);
    float s = 0.f, e[7];
#pragma unroll
    for (int j = 0; j < 7; j++) { e[j] = __expf(probs[tl][row * PST + j] - m); s += e[j]; }
    const float inv = 1.f / s;
#pragma unroll
    for (int j = 0; j < 7; j++) probs[tl][row * PST + j] = e[j] * inv;
  }
  e1_epi(acc1, xs1b, P[0], P[1]);
  __syncthreads();
  // Pipelined expert loop: {e2[ex] || e1_mfma[ex+1]} -> bar ->
  // {e1_epi[ex+1] -> P ; yr += pred} -> bar.
  for (int ex = 0; ex < 7; ++ex) {
    wexpert2d(P[0], P[1], xs2w + ex * 65536, xs2b + ex * 256, xfw + ex * 256,
              pred_part[0], pred_part[1]);
    if (ex < 6) e1_mfma(Q[0], Q[1], xs1w + (ex + 1) * 65536, acc1);
    __syncthreads();
    if (ex < 6) e1_epi(acc1, xs1b + (ex + 1) * 256, P[0], P[1]);
    if (t < 128) {
      const int tl = t >> 6, row = t & 63;
      float pr = 0.f;
#pragma unroll
      for (int w = 0; w < 8; w++) pr += pred_part[tl][w * 64 + row];
      yr += (pr + xfb[ex]) * probs[tl][row * PST + ex];
    }
    if (ex < 6) __syncthreads();
  }
  if (t < 128) out[r0g + t] = yr;
}

extern "C" void kernel_launch(void* const* d_in, const int* in_sizes, int n_in,
                              void* d_out, int out_size, void* d_ws, size_t ws_size,
                              hipStream_t stream) {
  (void)out_size; (void)n_in; (void)ws_size;
  const int   idx[N_CVT] = {1, 3, 5, 7, 9, 13, 17, 19};
  // KSIN folded into sine-layer weights (enc_s1, enc_s2, pol_s2, exp_s1, exp_s2)
  const float scl[N_CVT] = {KSIN, KSIN, 1.f, 1.f, 1.f, KSIN, KSIN, KSIN};
  unsigned off[N_CVT], cur = 0;
  CvtArgs a;
  for (int i = 0; i < N_CVT; i++) {
    off[i] = cur;
    a.src[i] = (const float*)d_in[idx[i]];
    a.off[i] = cur;
    a.n[i]   = (unsigned)in_sizes[idx[i]];
    a.scl[i] = scl[i];
    cur += ((unsigned)in_sizes[idx[i]] + 7u) & ~7u;  // 16B-align each array
  }
  unsigned short* dst = (unsigned short*)d_ws;
  hipLaunchKernelGGL(convert_kernel, dim3(256), dim3(256), 0, stream, a, dst);
  hipLaunchKernelGGL(moe_inr_kernel, dim3(65536 / 128), dim3(512), 0, stream,
      (const float*)d_in[0],
      dst + off[0], (const float*)d_in[2],
      dst + off[1], (const float*)d_in[4],
      dst + off[2], (const float*)d_in[6],
      dst + off[3], (const float*)d_in[8],
      dst + off[4], (const float*)d_in[10],
      (const float*)d_in[11], (const float*)d_in[12],
      dst + off[5], (const float*)d_in[14],
      (const float*)d_in[15], (const float*)d_in[16],
      dst + off[6], (const float*)d_in[18],
      dst + off[7], (const float*)d_in[20],
      (const float*)d_in[21], (const float*)d_in[22],
      (float*)d_out);
}